// Round 8
// baseline (911.878 us; speedup 1.0000x reference)
//
#include <hip/hip_runtime.h>
#include <hip/hip_bf16.h>

#define F_OUT 64
#define NEG_SLOPE 0.2f
#define SOFT_EPS 1e-16f
#define BW 64           // nodes per bucket (i_local fits in 8-bit field)
#define CH 4096         // edges per chunk
#define GT 512          // gather block threads (8 waves)

typedef short short8 __attribute__((ext_vector_type(8)));
typedef float floatx4 __attribute__((ext_vector_type(4)));
typedef unsigned long long u64;

__device__ __forceinline__ unsigned short f2bf_bits(float v) {
    __hip_bfloat16 hb = __float2bfloat16(v);
    return *(unsigned short*)&hb;
}
__device__ __forceinline__ float bf_bits2f(unsigned short u) {
    __hip_bfloat16 hb = *(__hip_bfloat16*)&u;
    return __bfloat162float(hb);
}

__device__ __forceinline__ float read_any(const void* src, int off, int bf) {
    return bf ? __bfloat162float(((const __hip_bfloat16*)src)[off])
              : ((const float*)src)[off];
}

// ---------- fused dtype detection + weight prep (single block) ----------
__global__ void prep_all(const unsigned* __restrict__ wbits, const unsigned* __restrict__ ebits,
                         const void* w1, const void* as1, const void* ad1, const void* b1,
                         const void* w2, const void* as2, const void* ad2, const void* b2,
                         unsigned short* __restrict__ wt1, unsigned short* __restrict__ wt2,
                         float* __restrict__ vecs, int n1, int n2, int K1,
                         int* __restrict__ flags) {
    __shared__ int cnt_bf, cnt_zero, sh_bf;
    int tid = threadIdx.x;
    if (tid == 0) { cnt_bf = 0; cnt_zero = 0; }
    __syncthreads();
    int lb = 0, lz = 0;
    for (int k = tid; k < 4096; k += 1024) {
        unsigned w = wbits[k];
        unsigned e = (w >> 7) & 0xFFu;
        if (e >= 0x60u && e <= 0x7Eu) lb++;
        if (ebits[2 * k + 1] == 0u) lz++;
    }
    atomicAdd(&cnt_bf, lb);
    atomicAdd(&cnt_zero, lz);
    __syncthreads();
    if (tid == 0) {
        int bf = (cnt_bf > 2048) ? 1 : 0;
        flags[0] = bf;
        flags[1] = (cnt_zero > 2048) ? 1 : 0;
        sh_bf = bf;
    }
    __syncthreads();
    int bf = sh_bf;
    int total = n1 + n2 + 384;
    for (int t = tid; t < total; t += 1024) {
        if (t < n1) {                       // wt1[n*K1 + k] = W1[k*64 + n]
            int n = t / K1, k = t - n * K1;
            wt1[t] = f2bf_bits(read_any(w1, k * F_OUT + n, bf));
        } else if (t < n1 + n2) {           // wt2[n*64 + k] = W2[k*64 + n]
            int u = t - n1;
            int n = u >> 6, k = u & 63;
            wt2[u] = f2bf_bits(read_any(w2, k * F_OUT + n, bf));
        } else {
            int u = t - n1 - n2;
            const void* src[6] = {as1, ad1, b1, as2, ad2, b2};
            vecs[u] = read_any(src[u >> 6], u & 63, bf);
        }
    }
}

__device__ __forceinline__ int get_idx(const void* ei, int i64, long long pos) {
    return i64 ? (int)((const long long*)ei)[pos] : ((const int*)ei)[pos];
}

// ---------- locality-aware bucket sort (64-node buckets), self-loops at t >= E ----------

// Per-chunk bucket histogram -> table[b * nchunks + chunk]  (bucket-major).
__global__ void bucket_count(const void* __restrict__ ei, int* __restrict__ table,
                             int E, int total, int NB, int nchunks,
                             const int* __restrict__ flags) {
    __shared__ int cnt[1024];
    for (int k = threadIdx.x; k < NB; k += 256) cnt[k] = 0;
    __syncthreads();
    int i64 = flags[1];
    int base = blockIdx.x * CH;
    int lim = base + CH < total ? base + CH : total;
    for (int t = base + threadIdx.x; t < lim; t += 256) {
        int i = t < E ? get_idx(ei, i64, (long long)E + t) : t - E;
        atomicAdd(&cnt[i / BW], 1);
    }
    __syncthreads();
    for (int k = threadIdx.x; k < NB; k += 256) table[k * nchunks + blockIdx.x] = cnt[k];
}

// ---- generic hierarchical exclusive scan ----
__global__ void scan_phaseA(const int* __restrict__ src, int* __restrict__ bsum, int n) {
    int idx = blockIdx.x * 1024 + threadIdx.x * 4;
    int s = 0;
#pragma unroll
    for (int j = 0; j < 4; ++j) { int k = idx + j; if (k < n) s += src[k]; }
#pragma unroll
    for (int off = 1; off < 64; off <<= 1) s += __shfl_xor(s, off);
    __shared__ int ws[4];
    int lane = threadIdx.x & 63, w = threadIdx.x >> 6;
    if (lane == 0) ws[w] = s;
    __syncthreads();
    if (threadIdx.x == 0) bsum[blockIdx.x] = ws[0] + ws[1] + ws[2] + ws[3];
}

__global__ void scan_phaseB(int* __restrict__ bsum, int nb) {
    int lane = threadIdx.x;  // 64 threads
    int carry = 0;
    for (int base = 0; base < nb; base += 64) {
        int idx = base + lane;
        int orig = (idx < nb) ? bsum[idx] : 0;
        int v = orig;
#pragma unroll
        for (int off = 1; off < 64; off <<= 1) {
            int t = __shfl_up(v, off);
            if (lane >= off) v += t;
        }
        int chunk_total = __shfl(v, 63);
        if (idx < nb) bsum[idx] = v - orig + carry;
        carry += chunk_total;
    }
}

// In-place safe: each block reads its own 1024 region before writing it.
__global__ void scan_phaseC(int* __restrict__ data, const int* __restrict__ bsum, int n) {
    int idx = blockIdx.x * 1024 + threadIdx.x * 4;
    int lane = threadIdx.x & 63, w = threadIdx.x >> 6;
    int d[4];
#pragma unroll
    for (int j = 0; j < 4; ++j) d[j] = (idx + j < n) ? data[idx + j] : 0;
    int tot = d[0] + d[1] + d[2] + d[3];
    int v = tot;
#pragma unroll
    for (int off = 1; off < 64; off <<= 1) {
        int t = __shfl_up(v, off);
        if (lane >= off) v += t;
    }
    __shared__ int wtot[4];
    if (lane == 63) wtot[w] = v;
    __syncthreads();
    int woff = 0;
    for (int k = 0; k < w; ++k) woff += wtot[k];
    int excl = v - tot + woff + bsum[blockIdx.x];
    int o[4];
    o[0] = excl; o[1] = o[0] + d[0]; o[2] = o[1] + d[1]; o[3] = o[2] + d[2];
#pragma unroll
    for (int j = 0; j < 4; ++j)
        if (idx + j < n) data[idx + j] = o[j];
}

// Per-chunk scatter into bucket-major staging: staged64[pos] = (i<<32)|j.
__global__ void stage_scatter(const void* __restrict__ ei, const int* __restrict__ table,
                              u64* __restrict__ staged64, int E, int total,
                              int NB, int nchunks, const int* __restrict__ flags) {
    __shared__ int cur[1024];
    for (int k = threadIdx.x; k < NB; k += 256) cur[k] = table[k * nchunks + blockIdx.x];
    __syncthreads();
    int i64 = flags[1];
    int base = blockIdx.x * CH;
    int lim = base + CH < total ? base + CH : total;
    for (int t = base + threadIdx.x; t < lim; t += 256) {
        int i = t < E ? get_idx(ei, i64, (long long)E + t) : t - E;
        int j = t < E ? get_idx(ei, i64, t) : t - E;
        int pos = atomicAdd(&cur[i / BW], 1);
        staged64[pos] = ((u64)(unsigned)i << 32) | (unsigned)j;
    }
}

// ---------- per-layer edge weights: staged2[p] = (f32bits(w)<<32)|(i_local<<24)|j ----------
__global__ void edge_weights(const u64* __restrict__ staged64, u64* __restrict__ staged2,
                             const float* __restrict__ a_s, const float* __restrict__ a_d,
                             int total) {
    int p = blockIdx.x * blockDim.x + threadIdx.x;
    if (p >= total) return;
    u64 u = staged64[p];
    int i = (int)(u >> 32);
    int j = (int)(u & 0xFFFFFFFFull);
    float e = a_s[j] + a_d[i];
    float w = __expf(e > 0.f ? e : NEG_SLOPE * e);
    staged2[p] = ((u64)__float_as_uint(w) << 32) |
                 ((unsigned)(i & (BW - 1)) << 24) | (unsigned)j;
}

// ---------- MFMA GEMM: h = x @ W (h stored bf16), fused attention dots ----------
template <int K>
__global__ void mfma_gemm(const void* __restrict__ xv, const unsigned short* __restrict__ Wt,
                          const float* __restrict__ att_s, const float* __restrict__ att_d,
                          unsigned short* __restrict__ h, float* __restrict__ a_s,
                          float* __restrict__ a_d, int N,
                          const int* __restrict__ flags, int in_mode) {
    int lane = threadIdx.x & 63;
    int m0 = (blockIdx.x * 4 + (threadIdx.x >> 6)) * 16;
    if (m0 >= N) return;
    int c = lane & 15, quad = lane >> 4;
    int arow = m0 + c;
    if (arow >= N) arow = N - 1;
    int bf = (in_mode == 2) ? flags[0] : in_mode;

    floatx4 acc0 = {0.f, 0.f, 0.f, 0.f};
    floatx4 acc1 = acc0, acc2 = acc0, acc3 = acc0;

    for (int kc = 0; kc < K; kc += 32) {
        int ka = kc + quad * 8;
        short8 a;
        if (bf) {
            a = *(const short8*)((const unsigned short*)xv + (size_t)arow * K + ka);
        } else {
            const float* xp = (const float*)xv + (size_t)arow * K + ka;
#pragma unroll
            for (int j = 0; j < 8; ++j) a[j] = (short)f2bf_bits(xp[j]);
        }
        short8 b0 = *(const short8*)(Wt + (size_t)(c)      * K + ka);
        short8 b1 = *(const short8*)(Wt + (size_t)(16 + c) * K + ka);
        short8 b2 = *(const short8*)(Wt + (size_t)(32 + c) * K + ka);
        short8 b3 = *(const short8*)(Wt + (size_t)(48 + c) * K + ka);
        acc0 = __builtin_amdgcn_mfma_f32_16x16x32_bf16(a, b0, acc0, 0, 0, 0);
        acc1 = __builtin_amdgcn_mfma_f32_16x16x32_bf16(a, b1, acc1, 0, 0, 0);
        acc2 = __builtin_amdgcn_mfma_f32_16x16x32_bf16(a, b2, acc2, 0, 0, 0);
        acc3 = __builtin_amdgcn_mfma_f32_16x16x32_bf16(a, b3, acc3, 0, 0, 0);
    }

    float as0 = att_s[c],      as1 = att_s[16 + c], as2 = att_s[32 + c], as3 = att_s[48 + c];
    float ad0 = att_d[c],      ad1 = att_d[16 + c], ad2 = att_d[32 + c], ad3 = att_d[48 + c];
#pragma unroll
    for (int reg = 0; reg < 4; ++reg) {
        int row = m0 + quad * 4 + reg;
        float vs = acc0[reg] * as0 + acc1[reg] * as1 + acc2[reg] * as2 + acc3[reg] * as3;
        float vd = acc0[reg] * ad0 + acc1[reg] * ad1 + acc2[reg] * ad2 + acc3[reg] * ad3;
#pragma unroll
        for (int off = 1; off < 16; off <<= 1) {
            vs += __shfl_xor(vs, off);
            vd += __shfl_xor(vd, off);
        }
        if (row < N) {
            if (c == 0) { a_s[row] = vs; a_d[row] = vd; }
            unsigned short* hr = h + (size_t)row * F_OUT + c;
            hr[0]  = f2bf_bits(acc0[reg]);
            hr[16] = f2bf_bits(acc1[reg]);
            hr[32] = f2bf_bits(acc2[reg]);
            hr[48] = f2bf_bits(acc3[reg]);
        }
    }
}

// ---------- edge-parallel gather: one block per 64-node bucket, LDS accumulation ----------
// 8 waves stride the bucket's edge segment, 4 independent edges in flight per wave.
// mode 0: x1_bf16 = bf16(relu(acc/sum + bias));  mode 1: final output per flags[0].
__global__ void __launch_bounds__(GT, 4)
bucket_gather(const u64* __restrict__ staged2, const int* __restrict__ table,
              const unsigned short* __restrict__ h, const float* __restrict__ bias,
              void* __restrict__ out, int N, int total, int NB, int nchunks,
              const int* __restrict__ flags, int mode) {
    __shared__ float acc[BW * F_OUT];
    __shared__ float se[BW];
    int b = blockIdx.x;
    int tid = threadIdx.x;
    int lane = tid & 63, wid = tid >> 6;   // 8 waves
    for (int k = tid; k < BW * F_OUT; k += GT) acc[k] = 0.f;
    if (tid < BW) se[tid] = 0.f;
    __syncthreads();
    int seg_beg = table[b * nchunks];
    int seg_end = (b + 1 < NB) ? table[(b + 1) * nchunks] : total;

    for (int p = seg_beg + wid * 4; p < seg_end; p += 8 * 4) {
        u64 u0 = staged2[p];
        u64 lo = u0 & 0xFFFFFFFFull;           // w=0 filler keeps tails branch-free
        u64 u1 = (p + 1 < seg_end) ? staged2[p + 1] : lo;
        u64 u2 = (p + 2 < seg_end) ? staged2[p + 2] : lo;
        u64 u3 = (p + 3 < seg_end) ? staged2[p + 3] : lo;
        int j0 = (int)(u0 & 0xFFFFFF), il0 = (int)((u0 >> 24) & 0xFF);
        int j1 = (int)(u1 & 0xFFFFFF), il1 = (int)((u1 >> 24) & 0xFF);
        int j2 = (int)(u2 & 0xFFFFFF), il2 = (int)((u2 >> 24) & 0xFF);
        int j3 = (int)(u3 & 0xFFFFFF), il3 = (int)((u3 >> 24) & 0xFF);
        float w0 = __uint_as_float((unsigned)(u0 >> 32));
        float w1 = __uint_as_float((unsigned)(u1 >> 32));
        float w2 = __uint_as_float((unsigned)(u2 >> 32));
        float w3 = __uint_as_float((unsigned)(u3 >> 32));
        float h0 = bf_bits2f(h[(size_t)j0 * F_OUT + lane]);
        float h1 = bf_bits2f(h[(size_t)j1 * F_OUT + lane]);
        float h2 = bf_bits2f(h[(size_t)j2 * F_OUT + lane]);
        float h3 = bf_bits2f(h[(size_t)j3 * F_OUT + lane]);
        atomicAdd(&acc[il0 * F_OUT + lane], w0 * h0);
        atomicAdd(&acc[il1 * F_OUT + lane], w1 * h1);
        atomicAdd(&acc[il2 * F_OUT + lane], w2 * h2);
        atomicAdd(&acc[il3 * F_OUT + lane], w3 * h3);
        if (lane == 0) {
            atomicAdd(&se[il0], w0);
            atomicAdd(&se[il1], w1);
            atomicAdd(&se[il2], w2);
            atomicAdd(&se[il3], w3);
        }
    }
    __syncthreads();

    int node0 = b * BW;
    int nn = N - node0; if (nn > BW) nn = BW;
    for (int idx = tid; idx < nn * F_OUT; idx += GT) {
        int nd = idx >> 6, col = idx & 63;
        float v = acc[idx] / (se[nd] + SOFT_EPS) + bias[col];
        size_t o = (size_t)(node0 + nd) * F_OUT + col;
        if (mode == 0) {
            ((unsigned short*)out)[o] = f2bf_bits(v > 0.f ? v : 0.f);
        } else {
            if (flags[0]) ((__hip_bfloat16*)out)[o] = __float2bfloat16(v);
            else          ((float*)out)[o] = v;
        }
    }
}

extern "C" void kernel_launch(void* const* d_in, const int* in_sizes, int n_in,
                              void* d_out, int out_size, void* d_ws, size_t ws_size,
                              hipStream_t stream) {
    const void* x   = d_in[0];
    const void* ei  = d_in[1];
    const void* W1  = d_in[2];
    const void* as1 = d_in[3];
    const void* ad1 = d_in[4];
    const void* b1  = d_in[5];
    const void* W2  = d_in[6];
    const void* as2 = d_in[7];
    const void* ad2 = d_in[8];
    const void* b2  = d_in[9];

    int E  = in_sizes[1] / 2;          // 800000
    int n1 = in_sizes[2];              // 128*64
    int n2 = in_sizes[6];              // 64*64
    int K1 = n1 / F_OUT;               // 128
    int N  = in_sizes[0] / K1;         // 50000
    int total = E + N;
    int NB = (N + BW - 1) / BW;        // 782 buckets
    int nchunks = (total + CH - 1) / CH; // 208 chunks
    int M = NB * nchunks;              // table size
    int nbM = (M + 1023) / 1024;

    size_t nf = (size_t)N * F_OUT;
    char* wsb = (char*)d_ws;
    unsigned short* h   = (unsigned short*)wsb;                 // nf bf16
    unsigned short* x1b = h + nf;                               // nf bf16
    unsigned short* wt1 = x1b + nf;                             // n1 bf16
    unsigned short* wt2 = wt1 + n1;                             // n2 bf16
    u64* staged64 = (u64*)(wt2 + n2);     // total u64 (byte offset %8 == 0)
    u64* staged2  = staged64 + total;     // total u64
    float* a_s  = (float*)(staged2 + total);
    float* a_d  = a_s + N;
    float* vecs = a_d + N;                                      // 384 f32
    float* cAs1 = vecs,       *cAd1 = vecs + 64,  *cB1 = vecs + 128;
    float* cAs2 = vecs + 192, *cAd2 = vecs + 256, *cB2 = vecs + 320;
    int* flags = (int*)(vecs + 384);
    int* table = flags + 8;               // M
    int* bsum  = table + M;               // nbM

    int blkGemm = (N + 63) / 64;       // 4 waves x 16 rows per block
    int blkEdge = (total + 255) / 256;

    prep_all<<<1, 1024, 0, stream>>>((const unsigned*)W1, (const unsigned*)ei,
                                     W1, as1, ad1, b1, W2, as2, ad2, b2,
                                     wt1, wt2, vecs, n1, n2, K1, flags);

    // ---- bucket sort of edges by dst/64 (no global atomics, full-line writes) ----
    bucket_count<<<nchunks, 256, 0, stream>>>(ei, table, E, total, NB, nchunks, flags);
    scan_phaseA<<<nbM, 256, 0, stream>>>(table, bsum, M);
    scan_phaseB<<<1, 64, 0, stream>>>(bsum, nbM);
    scan_phaseC<<<nbM, 256, 0, stream>>>(table, bsum, M);        // in-place exclusive scan
    stage_scatter<<<nchunks, 256, 0, stream>>>(ei, table, staged64, E, total, NB, nchunks, flags);

    // ---- layer 1 ----
    mfma_gemm<128><<<blkGemm, 256, 0, stream>>>(x, wt1, cAs1, cAd1, h, a_s, a_d, N, flags, 2);
    edge_weights<<<blkEdge, 256, 0, stream>>>(staged64, staged2, a_s, a_d, total);
    bucket_gather<<<NB, GT, 0, stream>>>(staged2, table, h, cB1, x1b, N, total, NB, nchunks, flags, 0);

    // ---- layer 2 ----
    mfma_gemm<64><<<blkGemm, 256, 0, stream>>>(x1b, wt2, cAs2, cAd2, h, a_s, a_d, N, flags, 1);
    edge_weights<<<blkEdge, 256, 0, stream>>>(staged64, staged2, a_s, a_d, total);
    bucket_gather<<<NB, GT, 0, stream>>>(staged2, table, h, cB2, d_out, N, total, NB, nchunks, flags, 1);
}

// Round 9
// 289.321 us; speedup vs baseline: 3.1518x; 3.1518x over previous
//
#include <hip/hip_runtime.h>
#include <hip/hip_bf16.h>

#define F_OUT 64
#define NEG_SLOPE 0.2f
#define SOFT_EPS 1e-16f
#define BW 256          // nodes per bucket (i_local fits in 8 bits)
#define CH 4096         // edges per chunk

typedef short short8 __attribute__((ext_vector_type(8)));
typedef float floatx4 __attribute__((ext_vector_type(4)));

__device__ __forceinline__ unsigned short f2bf_bits(float v) {
    __hip_bfloat16 hb = __float2bfloat16(v);
    return *(unsigned short*)&hb;
}
__device__ __forceinline__ float bf_bits2f(unsigned short u) {
    __hip_bfloat16 hb = *(__hip_bfloat16*)&u;
    return __bfloat162float(hb);
}

__device__ __forceinline__ float read_any(const void* src, int off, int bf) {
    return bf ? __bfloat162float(((const __hip_bfloat16*)src)[off])
              : ((const float*)src)[off];
}

// ---------- fused dtype detection + weight prep (single block) ----------
// flags[0] = 1 if float tensors are bf16, 0 if float32
// flags[1] = 1 if edge_index is int64, 0 if int32
__global__ void prep_all(const unsigned* __restrict__ wbits, const unsigned* __restrict__ ebits,
                         const void* w1, const void* as1, const void* ad1, const void* b1,
                         const void* w2, const void* as2, const void* ad2, const void* b2,
                         unsigned short* __restrict__ wt1, unsigned short* __restrict__ wt2,
                         float* __restrict__ vecs, int n1, int n2, int K1,
                         int* __restrict__ flags) {
    __shared__ int cnt_bf, cnt_zero, sh_bf;
    int tid = threadIdx.x;
    if (tid == 0) { cnt_bf = 0; cnt_zero = 0; }
    __syncthreads();
    int lb = 0, lz = 0;
    for (int k = tid; k < 4096; k += 1024) {
        unsigned w = wbits[k];
        unsigned e = (w >> 7) & 0xFFu;
        if (e >= 0x60u && e <= 0x7Eu) lb++;
        if (ebits[2 * k + 1] == 0u) lz++;
    }
    atomicAdd(&cnt_bf, lb);
    atomicAdd(&cnt_zero, lz);
    __syncthreads();
    if (tid == 0) {
        int bf = (cnt_bf > 2048) ? 1 : 0;
        flags[0] = bf;
        flags[1] = (cnt_zero > 2048) ? 1 : 0;
        sh_bf = bf;
    }
    __syncthreads();
    int bf = sh_bf;
    int total = n1 + n2 + 384;
    for (int t = tid; t < total; t += 1024) {
        if (t < n1) {                       // wt1[n*K1 + k] = W1[k*64 + n]
            int n = t / K1, k = t - n * K1;
            wt1[t] = f2bf_bits(read_any(w1, k * F_OUT + n, bf));
        } else if (t < n1 + n2) {           // wt2[n*64 + k] = W2[k*64 + n]
            int u = t - n1;
            int n = u >> 6, k = u & 63;
            wt2[u] = f2bf_bits(read_any(w2, k * F_OUT + n, bf));
        } else {
            int u = t - n1 - n2;
            const void* src[6] = {as1, ad1, b1, as2, ad2, b2};
            vecs[u] = read_any(src[u >> 6], u & 63, bf);
        }
    }
}

__device__ __forceinline__ int get_idx(const void* ei, int i64, long long pos) {
    return i64 ? (int)((const long long*)ei)[pos] : ((const int*)ei)[pos];
}

// ---------- locality-aware CSR build (counting sort by 256-node buckets) ----------
// Self-loops appended at t >= E (i = j = t - E).

// Per-chunk bucket histogram -> table[b * nchunks + chunk]  (bucket-major).
__global__ void bucket_count(const void* __restrict__ ei, int* __restrict__ table,
                             int E, int total, int NB, int nchunks,
                             const int* __restrict__ flags) {
    __shared__ int cnt[1024];
    for (int k = threadIdx.x; k < NB; k += 256) cnt[k] = 0;
    __syncthreads();
    int i64 = flags[1];
    int base = blockIdx.x * CH;
    int lim = base + CH < total ? base + CH : total;
    for (int t = base + threadIdx.x; t < lim; t += 256) {
        int i = t < E ? get_idx(ei, i64, (long long)E + t) : t - E;
        atomicAdd(&cnt[i >> 8], 1);
    }
    __syncthreads();
    for (int k = threadIdx.x; k < NB; k += 256) table[k * nchunks + blockIdx.x] = cnt[k];
}

// ---- single-block in-place exclusive scan of data[0..n); also writes *extra = extra_val ----
__global__ void scan_all(int* __restrict__ data, int n, int* __restrict__ extra, int extra_val) {
    __shared__ int wsum[16];
    int tid = threadIdx.x;             // 1024 threads, 16 waves
    int lane = tid & 63, w = tid >> 6;
    int chunk = (n + 1023) >> 10;
    int s = tid * chunk;
    int e = s + chunk < n ? s + chunk : n;
    int sum = 0;
    for (int k = s; k < e; ++k) sum += data[k];
    int v = sum;
#pragma unroll
    for (int off = 1; off < 64; off <<= 1) {
        int t = __shfl_up(v, off);
        if (lane >= off) v += t;
    }
    if (lane == 63) wsum[w] = v;
    __syncthreads();
    int woff = 0;
    for (int k = 0; k < w; ++k) woff += wsum[k];
    int run = v - sum + woff;          // exclusive prefix at chunk start
    for (int k = s; k < e; ++k) { int d = data[k]; data[k] = run; run += d; }
    if (tid == 1023 && extra) *extra = extra_val;
}

// Per-chunk scatter into bucket-major staging: staged[pos] = (i_local<<24) | j.
__global__ void stage_scatter(const void* __restrict__ ei, const int* __restrict__ table,
                              unsigned* __restrict__ staged, int E, int total,
                              int NB, int nchunks, const int* __restrict__ flags) {
    __shared__ int cur[1024];
    for (int k = threadIdx.x; k < NB; k += 256) cur[k] = table[k * nchunks + blockIdx.x];
    __syncthreads();
    int i64 = flags[1];
    int base = blockIdx.x * CH;
    int lim = base + CH < total ? base + CH : total;
    for (int t = base + threadIdx.x; t < lim; t += 256) {
        int i = t < E ? get_idx(ei, i64, (long long)E + t) : t - E;
        int j = t < E ? get_idx(ei, i64, t) : t - E;
        int pos = atomicAdd(&cur[i >> 8], 1);
        staged[pos] = ((unsigned)(i & 255) << 24) | (unsigned)j;
    }
}

// One block per bucket: LDS degree hist -> LDS scan -> row_ptr and in-segment eidx.
__global__ void bucket_csr(const unsigned* __restrict__ staged, const int* __restrict__ table,
                           int* __restrict__ row_ptr, int* __restrict__ eidx,
                           int N, int total, int NB, int nchunks) {
    __shared__ int ldeg[BW];
    __shared__ int lcur[BW];
    __shared__ int wtot[4];
    int b = blockIdx.x;
    int t = threadIdx.x;
    int seg_beg = table[b * nchunks];
    int seg_end = (b + 1 < NB) ? table[(b + 1) * nchunks] : total;
    ldeg[t] = 0;
    __syncthreads();
    for (int p = seg_beg + t; p < seg_end; p += 256)
        atomicAdd(&ldeg[staged[p] >> 24], 1);
    __syncthreads();
    int lane = t & 63, w = t >> 6;
    int d = ldeg[t];
    int v = d;
#pragma unroll
    for (int off = 1; off < 64; off <<= 1) {
        int u = __shfl_up(v, off);
        if (lane >= off) v += u;
    }
    if (lane == 63) wtot[w] = v;
    __syncthreads();
    int woff = 0;
    for (int k = 0; k < w; ++k) woff += wtot[k];
    int excl = v - d + woff;
    int node = b * BW + t;
    if (node < N) row_ptr[node] = seg_beg + excl;
    lcur[t] = excl;
    __syncthreads();
    for (int p = seg_beg + t; p < seg_end; p += 256) {
        unsigned pk = staged[p];
        int pos = atomicAdd(&lcur[pk >> 24], 1);
        eidx[seg_beg + pos] = (int)(pk & 0xFFFFFFu);
    }
}

// ---------- MFMA GEMM: h = x @ W (h stored bf16), fused attention dots ----------
template <int K>
__global__ void mfma_gemm(const void* __restrict__ xv, const unsigned short* __restrict__ Wt,
                          const float* __restrict__ att_s, const float* __restrict__ att_d,
                          unsigned short* __restrict__ h, float* __restrict__ a_s,
                          float* __restrict__ a_d, int N,
                          const int* __restrict__ flags, int in_mode) {
    int lane = threadIdx.x & 63;
    int m0 = (blockIdx.x * 4 + (threadIdx.x >> 6)) * 16;
    if (m0 >= N) return;
    int c = lane & 15, quad = lane >> 4;
    int arow = m0 + c;
    if (arow >= N) arow = N - 1;
    int bf = (in_mode == 2) ? flags[0] : in_mode;

    floatx4 acc0 = {0.f, 0.f, 0.f, 0.f};
    floatx4 acc1 = acc0, acc2 = acc0, acc3 = acc0;

    for (int kc = 0; kc < K; kc += 32) {
        int ka = kc + quad * 8;
        short8 a;
        if (bf) {
            a = *(const short8*)((const unsigned short*)xv + (size_t)arow * K + ka);
        } else {
            const float* xp = (const float*)xv + (size_t)arow * K + ka;
#pragma unroll
            for (int j = 0; j < 8; ++j) a[j] = (short)f2bf_bits(xp[j]);
        }
        short8 b0 = *(const short8*)(Wt + (size_t)(c)      * K + ka);
        short8 b1 = *(const short8*)(Wt + (size_t)(16 + c) * K + ka);
        short8 b2 = *(const short8*)(Wt + (size_t)(32 + c) * K + ka);
        short8 b3 = *(const short8*)(Wt + (size_t)(48 + c) * K + ka);
        acc0 = __builtin_amdgcn_mfma_f32_16x16x32_bf16(a, b0, acc0, 0, 0, 0);
        acc1 = __builtin_amdgcn_mfma_f32_16x16x32_bf16(a, b1, acc1, 0, 0, 0);
        acc2 = __builtin_amdgcn_mfma_f32_16x16x32_bf16(a, b2, acc2, 0, 0, 0);
        acc3 = __builtin_amdgcn_mfma_f32_16x16x32_bf16(a, b3, acc3, 0, 0, 0);
    }

    float as0 = att_s[c],      as1 = att_s[16 + c], as2 = att_s[32 + c], as3 = att_s[48 + c];
    float ad0 = att_d[c],      ad1 = att_d[16 + c], ad2 = att_d[32 + c], ad3 = att_d[48 + c];
#pragma unroll
    for (int reg = 0; reg < 4; ++reg) {
        int row = m0 + quad * 4 + reg;
        float vs = acc0[reg] * as0 + acc1[reg] * as1 + acc2[reg] * as2 + acc3[reg] * as3;
        float vd = acc0[reg] * ad0 + acc1[reg] * ad1 + acc2[reg] * ad2 + acc3[reg] * ad3;
#pragma unroll
        for (int off = 1; off < 16; off <<= 1) {
            vs += __shfl_xor(vs, off);
            vd += __shfl_xor(vd, off);
        }
        if (row < N) {
            if (c == 0) { a_s[row] = vs; a_d[row] = vd; }
            unsigned short* hr = h + (size_t)row * F_OUT + c;
            hr[0]  = f2bf_bits(acc0[reg]);
            hr[16] = f2bf_bits(acc1[reg]);
            hr[32] = f2bf_bits(acc2[reg]);
            hr[48] = f2bf_bits(acc3[reg]);
        }
    }
}

// ---------- fused softmax + gather + bias; 1 wave per node ----------
// Lane-parallel edge metadata + shuffle broadcast; 8-deep independent h-loads.
// mode 0: x1_bf16 = bf16(relu(acc/sum + bias))
// mode 1: out = acc/sum + bias, stored bf16 or f32 per flags[0]
__global__ void node_gather(const int* __restrict__ row_ptr, const int* __restrict__ eidx,
                            const float* __restrict__ a_s, const float* __restrict__ a_d,
                            const unsigned short* __restrict__ h, const float* __restrict__ bias,
                            void* __restrict__ out, int N,
                            const int* __restrict__ flags, int mode) {
    int lane = threadIdx.x & 63;
    int i = blockIdx.x * 4 + (threadIdx.x >> 6);
    if (i >= N) return;
    int beg = row_ptr[i];
    int end = row_ptr[i + 1];
    float ad = a_d[i];
    float se = 0.f;
    float acc0 = 0.f, acc1 = 0.f, acc2 = 0.f, acc3 = 0.f;
    float acc4 = 0.f, acc5 = 0.f, acc6 = 0.f, acc7 = 0.f;
    for (int p = beg; p < end; p += 64) {
        int tile = end - p; if (tile > 64) tile = 64;
        int j = eidx[p + (lane < tile ? lane : tile - 1)];
        float w = 0.f;
        if (lane < tile) {
            float e = a_s[j] + ad;
            w = __expf(e > 0.f ? e : NEG_SLOPE * e);
        }
        se += w;
        int e = 0;
        for (; e + 8 <= tile; e += 8) {
            int j0 = __shfl(j, e),     j1 = __shfl(j, e + 1);
            int j2 = __shfl(j, e + 2), j3 = __shfl(j, e + 3);
            int j4 = __shfl(j, e + 4), j5 = __shfl(j, e + 5);
            int j6 = __shfl(j, e + 6), j7 = __shfl(j, e + 7);
            float w0 = __shfl(w, e),     w1 = __shfl(w, e + 1);
            float w2 = __shfl(w, e + 2), w3 = __shfl(w, e + 3);
            float w4 = __shfl(w, e + 4), w5 = __shfl(w, e + 5);
            float w6 = __shfl(w, e + 6), w7 = __shfl(w, e + 7);
            float h0 = bf_bits2f(h[(size_t)j0 * F_OUT + lane]);
            float h1 = bf_bits2f(h[(size_t)j1 * F_OUT + lane]);
            float h2 = bf_bits2f(h[(size_t)j2 * F_OUT + lane]);
            float h3 = bf_bits2f(h[(size_t)j3 * F_OUT + lane]);
            float h4 = bf_bits2f(h[(size_t)j4 * F_OUT + lane]);
            float h5 = bf_bits2f(h[(size_t)j5 * F_OUT + lane]);
            float h6 = bf_bits2f(h[(size_t)j6 * F_OUT + lane]);
            float h7 = bf_bits2f(h[(size_t)j7 * F_OUT + lane]);
            acc0 += w0 * h0; acc1 += w1 * h1; acc2 += w2 * h2; acc3 += w3 * h3;
            acc4 += w4 * h4; acc5 += w5 * h5; acc6 += w6 * h6; acc7 += w7 * h7;
        }
        for (; e < tile; ++e) {
            int jj = __shfl(j, e);
            float ww = __shfl(w, e);
            acc0 += ww * bf_bits2f(h[(size_t)jj * F_OUT + lane]);
        }
    }
#pragma unroll
    for (int off = 1; off < 64; off <<= 1) se += __shfl_xor(se, off);
    float acc = ((acc0 + acc1) + (acc2 + acc3)) + ((acc4 + acc5) + (acc6 + acc7));
    float v = acc / (se + SOFT_EPS) + bias[lane];
    if (mode == 0) {
        ((unsigned short*)out)[(size_t)i * F_OUT + lane] = f2bf_bits(v > 0.f ? v : 0.f);
    } else {
        if (flags[0]) ((__hip_bfloat16*)out)[(size_t)i * F_OUT + lane] = __float2bfloat16(v);
        else          ((float*)out)[(size_t)i * F_OUT + lane] = v;
    }
}

extern "C" void kernel_launch(void* const* d_in, const int* in_sizes, int n_in,
                              void* d_out, int out_size, void* d_ws, size_t ws_size,
                              hipStream_t stream) {
    const void* x   = d_in[0];
    const void* ei  = d_in[1];
    const void* W1  = d_in[2];
    const void* as1 = d_in[3];
    const void* ad1 = d_in[4];
    const void* b1  = d_in[5];
    const void* W2  = d_in[6];
    const void* as2 = d_in[7];
    const void* ad2 = d_in[8];
    const void* b2  = d_in[9];

    int E  = in_sizes[1] / 2;          // 800000
    int n1 = in_sizes[2];              // 128*64
    int n2 = in_sizes[6];              // 64*64
    int K1 = n1 / F_OUT;               // 128
    int N  = in_sizes[0] / K1;         // 50000
    int total = E + N;
    int NB = (N + BW - 1) / BW;        // 196 buckets
    int nchunks = (total + CH - 1) / CH; // 208 chunks
    int M = NB * nchunks;              // table size

    size_t nf = (size_t)N * F_OUT;
    char* wsb = (char*)d_ws;
    unsigned short* h   = (unsigned short*)wsb;                 // nf bf16
    unsigned short* x1b = h + nf;                               // nf bf16
    unsigned short* wt1 = x1b + nf;                             // n1 bf16
    unsigned short* wt2 = wt1 + n1;                             // n2 bf16
    float* a_s  = (float*)(wt2 + n2 + ((n1 + n2) & 1));         // N f32 (align)
    float* a_d  = a_s + N;
    float* vecs = a_d + N;                                      // 384 f32
    float* cAs1 = vecs,       *cAd1 = vecs + 64,  *cB1 = vecs + 128;
    float* cAs2 = vecs + 192, *cAd2 = vecs + 256, *cB2 = vecs + 320;
    int* flags    = (int*)(vecs + 384);
    int* row_ptr  = flags + 8;            // N+1
    int* eidx     = row_ptr + N + 1;      // total
    unsigned* staged = (unsigned*)(eidx + total); // total
    int* table    = (int*)(staged + total);       // M

    int blkGemm = (N + 63) / 64;       // 4 waves x 16 rows per block
    int blkNode = (N + 3) / 4;

    prep_all<<<1, 1024, 0, stream>>>((const unsigned*)W1, (const unsigned*)ei,
                                     W1, as1, ad1, b1, W2, as2, ad2, b2,
                                     wt1, wt2, vecs, n1, n2, K1, flags);

    // ---- CSR build: bucket counting sort (no global atomics) ----
    bucket_count<<<nchunks, 256, 0, stream>>>(ei, table, E, total, NB, nchunks, flags);
    scan_all<<<1, 1024, 0, stream>>>(table, M, row_ptr + N, total);  // row_ptr[N] = E+N
    stage_scatter<<<nchunks, 256, 0, stream>>>(ei, table, staged, E, total, NB, nchunks, flags);
    bucket_csr<<<NB, 256, 0, stream>>>(staged, table, row_ptr, eidx, N, total, NB, nchunks);

    // ---- layer 1 ----
    mfma_gemm<128><<<blkGemm, 256, 0, stream>>>(x, wt1, cAs1, cAd1, h, a_s, a_d, N, flags, 2);
    node_gather<<<blkNode, 256, 0, stream>>>(row_ptr, eidx, a_s, a_d, h, cB1, x1b, N, flags, 0);

    // ---- layer 2 ----
    mfma_gemm<64><<<blkGemm, 256, 0, stream>>>(x1b, wt2, cAs2, cAd2, h, a_s, a_d, N, flags, 1);
    node_gather<<<blkNode, 256, 0, stream>>>(row_ptr, eidx, a_s, a_d, h, cB2, d_out, N, flags, 1);
}

// Round 10
// 232.401 us; speedup vs baseline: 3.9237x; 1.2449x over previous
//
#include <hip/hip_runtime.h>
#include <hip/hip_bf16.h>

#define F_OUT 64
#define NEG_SLOPE 0.2f
#define SOFT_EPS 1e-16f
#define BW 256          // nodes per bucket (i_local fits in 8 bits)
#define CH 4096         // edges per chunk

typedef short short8 __attribute__((ext_vector_type(8)));
typedef float floatx4 __attribute__((ext_vector_type(4)));

__device__ __forceinline__ unsigned short f2bf_bits(float v) {
    __hip_bfloat16 hb = __float2bfloat16(v);
    return *(unsigned short*)&hb;
}
__device__ __forceinline__ float bf_bits2f(unsigned short u) {
    __hip_bfloat16 hb = *(__hip_bfloat16*)&u;
    return __bfloat162float(hb);
}

__device__ __forceinline__ float read_any(const void* src, int off, int bf) {
    return bf ? __bfloat162float(((const __hip_bfloat16*)src)[off])
              : ((const float*)src)[off];
}

// ---------- fused dtype detection + weight prep (single block) ----------
// flags[0] = 1 if float tensors are bf16, 0 if float32
// flags[1] = 1 if edge_index is int64, 0 if int32
__global__ void prep_all(const unsigned* __restrict__ wbits, const unsigned* __restrict__ ebits,
                         const void* w1, const void* as1, const void* ad1, const void* b1,
                         const void* w2, const void* as2, const void* ad2, const void* b2,
                         unsigned short* __restrict__ wt1, unsigned short* __restrict__ wt2,
                         float* __restrict__ vecs, int n1, int n2, int K1,
                         int* __restrict__ flags) {
    __shared__ int cnt_bf, cnt_zero, sh_bf;
    int tid = threadIdx.x;
    if (tid == 0) { cnt_bf = 0; cnt_zero = 0; }
    __syncthreads();
    int lb = 0, lz = 0;
    for (int k = tid; k < 4096; k += 1024) {
        unsigned w = wbits[k];
        unsigned e = (w >> 7) & 0xFFu;
        if (e >= 0x60u && e <= 0x7Eu) lb++;
        if (ebits[2 * k + 1] == 0u) lz++;
    }
    atomicAdd(&cnt_bf, lb);
    atomicAdd(&cnt_zero, lz);
    __syncthreads();
    if (tid == 0) {
        int bf = (cnt_bf > 2048) ? 1 : 0;
        flags[0] = bf;
        flags[1] = (cnt_zero > 2048) ? 1 : 0;
        sh_bf = bf;
    }
    __syncthreads();
    int bf = sh_bf;
    int total = n1 + n2 + 384;
    for (int t = tid; t < total; t += 1024) {
        if (t < n1) {                       // wt1[n*K1 + k] = W1[k*64 + n]
            int n = t / K1, k = t - n * K1;
            wt1[t] = f2bf_bits(read_any(w1, k * F_OUT + n, bf));
        } else if (t < n1 + n2) {           // wt2[n*64 + k] = W2[k*64 + n]
            int u = t - n1;
            int n = u >> 6, k = u & 63;
            wt2[u] = f2bf_bits(read_any(w2, k * F_OUT + n, bf));
        } else {
            int u = t - n1 - n2;
            const void* src[6] = {as1, ad1, b1, as2, ad2, b2};
            vecs[u] = read_any(src[u >> 6], u & 63, bf);
        }
    }
}

__device__ __forceinline__ int get_idx(const void* ei, int i64, long long pos) {
    return i64 ? (int)((const long long*)ei)[pos] : ((const int*)ei)[pos];
}

// ---------- locality-aware CSR build (counting sort by 256-node buckets) ----------
// Self-loops appended at t >= E (i = j = t - E).

// Per-chunk bucket histogram -> table[b * nchunks + chunk]  (bucket-major).
__global__ void bucket_count(const void* __restrict__ ei, int* __restrict__ table,
                             int E, int total, int NB, int nchunks,
                             const int* __restrict__ flags) {
    __shared__ int cnt[1024];
    for (int k = threadIdx.x; k < NB; k += 256) cnt[k] = 0;
    __syncthreads();
    int i64 = flags[1];
    int base = blockIdx.x * CH;
    int lim = base + CH < total ? base + CH : total;
    for (int t = base + threadIdx.x; t < lim; t += 256) {
        int i = t < E ? get_idx(ei, i64, (long long)E + t) : t - E;
        atomicAdd(&cnt[i >> 8], 1);
    }
    __syncthreads();
    for (int k = threadIdx.x; k < NB; k += 256) table[k * nchunks + blockIdx.x] = cnt[k];
}

// ---- hierarchical exclusive scan (parallel across blocks; R9's single-block
// scan_all was a 65 µs one-CU latency trap — keep this 3-phase form) ----
__global__ void scan_phaseA(const int* __restrict__ src, int* __restrict__ bsum, int n) {
    int idx = blockIdx.x * 1024 + threadIdx.x * 4;
    int s = 0;
#pragma unroll
    for (int j = 0; j < 4; ++j) { int k = idx + j; if (k < n) s += src[k]; }
#pragma unroll
    for (int off = 1; off < 64; off <<= 1) s += __shfl_xor(s, off);
    __shared__ int ws[4];
    int lane = threadIdx.x & 63, w = threadIdx.x >> 6;
    if (lane == 0) ws[w] = s;
    __syncthreads();
    if (threadIdx.x == 0) bsum[blockIdx.x] = ws[0] + ws[1] + ws[2] + ws[3];
}

// One wave; also writes *extra = extra_val (row_ptr[N] = E+N).
__global__ void scan_phaseB(int* __restrict__ bsum, int nb,
                            int* __restrict__ extra, int extra_val) {
    int lane = threadIdx.x;  // 64 threads
    int carry = 0;
    for (int base = 0; base < nb; base += 64) {
        int idx = base + lane;
        int orig = (idx < nb) ? bsum[idx] : 0;
        int v = orig;
#pragma unroll
        for (int off = 1; off < 64; off <<= 1) {
            int t = __shfl_up(v, off);
            if (lane >= off) v += t;
        }
        int chunk_total = __shfl(v, 63);
        if (idx < nb) bsum[idx] = v - orig + carry;
        carry += chunk_total;
    }
    if (lane == 0 && extra) *extra = extra_val;
}

// In-place safe: each block reads its own 1024 region before writing it.
__global__ void scan_phaseC(int* __restrict__ data, const int* __restrict__ bsum, int n) {
    int idx = blockIdx.x * 1024 + threadIdx.x * 4;
    int lane = threadIdx.x & 63, w = threadIdx.x >> 6;
    int d[4];
#pragma unroll
    for (int j = 0; j < 4; ++j) d[j] = (idx + j < n) ? data[idx + j] : 0;
    int tot = d[0] + d[1] + d[2] + d[3];
    int v = tot;
#pragma unroll
    for (int off = 1; off < 64; off <<= 1) {
        int t = __shfl_up(v, off);
        if (lane >= off) v += t;
    }
    __shared__ int wtot[4];
    if (lane == 63) wtot[w] = v;
    __syncthreads();
    int woff = 0;
    for (int k = 0; k < w; ++k) woff += wtot[k];
    int excl = v - tot + woff + bsum[blockIdx.x];
    int o[4];
    o[0] = excl; o[1] = o[0] + d[0]; o[2] = o[1] + d[1]; o[3] = o[2] + d[2];
#pragma unroll
    for (int j = 0; j < 4; ++j)
        if (idx + j < n) data[idx + j] = o[j];
}

// Per-chunk scatter into bucket-major staging: staged[pos] = (i_local<<24) | j.
__global__ void stage_scatter(const void* __restrict__ ei, const int* __restrict__ table,
                              unsigned* __restrict__ staged, int E, int total,
                              int NB, int nchunks, const int* __restrict__ flags) {
    __shared__ int cur[1024];
    for (int k = threadIdx.x; k < NB; k += 256) cur[k] = table[k * nchunks + blockIdx.x];
    __syncthreads();
    int i64 = flags[1];
    int base = blockIdx.x * CH;
    int lim = base + CH < total ? base + CH : total;
    for (int t = base + threadIdx.x; t < lim; t += 256) {
        int i = t < E ? get_idx(ei, i64, (long long)E + t) : t - E;
        int j = t < E ? get_idx(ei, i64, t) : t - E;
        int pos = atomicAdd(&cur[i >> 8], 1);
        staged[pos] = ((unsigned)(i & 255) << 24) | (unsigned)j;
    }
}

// One block per bucket: LDS degree hist -> LDS scan -> row_ptr and in-segment eidx.
__global__ void bucket_csr(const unsigned* __restrict__ staged, const int* __restrict__ table,
                           int* __restrict__ row_ptr, int* __restrict__ eidx,
                           int N, int total, int NB, int nchunks) {
    __shared__ int ldeg[BW];
    __shared__ int lcur[BW];
    __shared__ int wtot[4];
    int b = blockIdx.x;
    int t = threadIdx.x;
    int seg_beg = table[b * nchunks];
    int seg_end = (b + 1 < NB) ? table[(b + 1) * nchunks] : total;
    ldeg[t] = 0;
    __syncthreads();
    for (int p = seg_beg + t; p < seg_end; p += 256)
        atomicAdd(&ldeg[staged[p] >> 24], 1);
    __syncthreads();
    int lane = t & 63, w = t >> 6;
    int d = ldeg[t];
    int v = d;
#pragma unroll
    for (int off = 1; off < 64; off <<= 1) {
        int u = __shfl_up(v, off);
        if (lane >= off) v += u;
    }
    if (lane == 63) wtot[w] = v;
    __syncthreads();
    int woff = 0;
    for (int k = 0; k < w; ++k) woff += wtot[k];
    int excl = v - d + woff;
    int node = b * BW + t;
    if (node < N) row_ptr[node] = seg_beg + excl;
    lcur[t] = excl;
    __syncthreads();
    for (int p = seg_beg + t; p < seg_end; p += 256) {
        unsigned pk = staged[p];
        int pos = atomicAdd(&lcur[pk >> 24], 1);
        eidx[seg_beg + pos] = (int)(pk & 0xFFFFFFu);
    }
}

// ---------- MFMA GEMM: h = x @ W (h stored bf16), fused attention dots ----------
template <int K>
__global__ void mfma_gemm(const void* __restrict__ xv, const unsigned short* __restrict__ Wt,
                          const float* __restrict__ att_s, const float* __restrict__ att_d,
                          unsigned short* __restrict__ h, float* __restrict__ a_s,
                          float* __restrict__ a_d, int N,
                          const int* __restrict__ flags, int in_mode) {
    int lane = threadIdx.x & 63;
    int m0 = (blockIdx.x * 4 + (threadIdx.x >> 6)) * 16;
    if (m0 >= N) return;
    int c = lane & 15, quad = lane >> 4;
    int arow = m0 + c;
    if (arow >= N) arow = N - 1;
    int bf = (in_mode == 2) ? flags[0] : in_mode;

    floatx4 acc0 = {0.f, 0.f, 0.f, 0.f};
    floatx4 acc1 = acc0, acc2 = acc0, acc3 = acc0;

    for (int kc = 0; kc < K; kc += 32) {
        int ka = kc + quad * 8;
        short8 a;
        if (bf) {
            a = *(const short8*)((const unsigned short*)xv + (size_t)arow * K + ka);
        } else {
            const float* xp = (const float*)xv + (size_t)arow * K + ka;
#pragma unroll
            for (int j = 0; j < 8; ++j) a[j] = (short)f2bf_bits(xp[j]);
        }
        short8 b0 = *(const short8*)(Wt + (size_t)(c)      * K + ka);
        short8 b1 = *(const short8*)(Wt + (size_t)(16 + c) * K + ka);
        short8 b2 = *(const short8*)(Wt + (size_t)(32 + c) * K + ka);
        short8 b3 = *(const short8*)(Wt + (size_t)(48 + c) * K + ka);
        acc0 = __builtin_amdgcn_mfma_f32_16x16x32_bf16(a, b0, acc0, 0, 0, 0);
        acc1 = __builtin_amdgcn_mfma_f32_16x16x32_bf16(a, b1, acc1, 0, 0, 0);
        acc2 = __builtin_amdgcn_mfma_f32_16x16x32_bf16(a, b2, acc2, 0, 0, 0);
        acc3 = __builtin_amdgcn_mfma_f32_16x16x32_bf16(a, b3, acc3, 0, 0, 0);
    }

    float as0 = att_s[c],      as1 = att_s[16 + c], as2 = att_s[32 + c], as3 = att_s[48 + c];
    float ad0 = att_d[c],      ad1 = att_d[16 + c], ad2 = att_d[32 + c], ad3 = att_d[48 + c];
#pragma unroll
    for (int reg = 0; reg < 4; ++reg) {
        int row = m0 + quad * 4 + reg;
        float vs = acc0[reg] * as0 + acc1[reg] * as1 + acc2[reg] * as2 + acc3[reg] * as3;
        float vd = acc0[reg] * ad0 + acc1[reg] * ad1 + acc2[reg] * ad2 + acc3[reg] * ad3;
#pragma unroll
        for (int off = 1; off < 16; off <<= 1) {
            vs += __shfl_xor(vs, off);
            vd += __shfl_xor(vd, off);
        }
        if (row < N) {
            if (c == 0) { a_s[row] = vs; a_d[row] = vd; }
            unsigned short* hr = h + (size_t)row * F_OUT + c;
            hr[0]  = f2bf_bits(acc0[reg]);
            hr[16] = f2bf_bits(acc1[reg]);
            hr[32] = f2bf_bits(acc2[reg]);
            hr[48] = f2bf_bits(acc3[reg]);
        }
    }
}

// ---------- fused softmax + gather + bias; 1 wave per node ----------
// Lane-parallel edge metadata + shuffle broadcast; 8-deep independent h-loads.
// mode 0: x1_bf16 = bf16(relu(acc/sum + bias))
// mode 1: out = acc/sum + bias, stored bf16 or f32 per flags[0]
__global__ void node_gather(const int* __restrict__ row_ptr, const int* __restrict__ eidx,
                            const float* __restrict__ a_s, const float* __restrict__ a_d,
                            const unsigned short* __restrict__ h, const float* __restrict__ bias,
                            void* __restrict__ out, int N,
                            const int* __restrict__ flags, int mode) {
    int lane = threadIdx.x & 63;
    int i = blockIdx.x * 4 + (threadIdx.x >> 6);
    if (i >= N) return;
    int beg = row_ptr[i];
    int end = row_ptr[i + 1];
    float ad = a_d[i];
    float se = 0.f;
    float acc0 = 0.f, acc1 = 0.f, acc2 = 0.f, acc3 = 0.f;
    float acc4 = 0.f, acc5 = 0.f, acc6 = 0.f, acc7 = 0.f;
    for (int p = beg; p < end; p += 64) {
        int tile = end - p; if (tile > 64) tile = 64;
        int j = eidx[p + (lane < tile ? lane : tile - 1)];
        float w = 0.f;
        if (lane < tile) {
            float e = a_s[j] + ad;
            w = __expf(e > 0.f ? e : NEG_SLOPE * e);
        }
        se += w;
        int e = 0;
        for (; e + 8 <= tile; e += 8) {
            int j0 = __shfl(j, e),     j1 = __shfl(j, e + 1);
            int j2 = __shfl(j, e + 2), j3 = __shfl(j, e + 3);
            int j4 = __shfl(j, e + 4), j5 = __shfl(j, e + 5);
            int j6 = __shfl(j, e + 6), j7 = __shfl(j, e + 7);
            float w0 = __shfl(w, e),     w1 = __shfl(w, e + 1);
            float w2 = __shfl(w, e + 2), w3 = __shfl(w, e + 3);
            float w4 = __shfl(w, e + 4), w5 = __shfl(w, e + 5);
            float w6 = __shfl(w, e + 6), w7 = __shfl(w, e + 7);
            float h0 = bf_bits2f(h[(size_t)j0 * F_OUT + lane]);
            float h1 = bf_bits2f(h[(size_t)j1 * F_OUT + lane]);
            float h2 = bf_bits2f(h[(size_t)j2 * F_OUT + lane]);
            float h3 = bf_bits2f(h[(size_t)j3 * F_OUT + lane]);
            float h4 = bf_bits2f(h[(size_t)j4 * F_OUT + lane]);
            float h5 = bf_bits2f(h[(size_t)j5 * F_OUT + lane]);
            float h6 = bf_bits2f(h[(size_t)j6 * F_OUT + lane]);
            float h7 = bf_bits2f(h[(size_t)j7 * F_OUT + lane]);
            acc0 += w0 * h0; acc1 += w1 * h1; acc2 += w2 * h2; acc3 += w3 * h3;
            acc4 += w4 * h4; acc5 += w5 * h5; acc6 += w6 * h6; acc7 += w7 * h7;
        }
        for (; e < tile; ++e) {
            int jj = __shfl(j, e);
            float ww = __shfl(w, e);
            acc0 += ww * bf_bits2f(h[(size_t)jj * F_OUT + lane]);
        }
    }
#pragma unroll
    for (int off = 1; off < 64; off <<= 1) se += __shfl_xor(se, off);
    float acc = ((acc0 + acc1) + (acc2 + acc3)) + ((acc4 + acc5) + (acc6 + acc7));
    float v = acc / (se + SOFT_EPS) + bias[lane];
    if (mode == 0) {
        ((unsigned short*)out)[(size_t)i * F_OUT + lane] = f2bf_bits(v > 0.f ? v : 0.f);
    } else {
        if (flags[0]) ((__hip_bfloat16*)out)[(size_t)i * F_OUT + lane] = __float2bfloat16(v);
        else          ((float*)out)[(size_t)i * F_OUT + lane] = v;
    }
}

extern "C" void kernel_launch(void* const* d_in, const int* in_sizes, int n_in,
                              void* d_out, int out_size, void* d_ws, size_t ws_size,
                              hipStream_t stream) {
    const void* x   = d_in[0];
    const void* ei  = d_in[1];
    const void* W1  = d_in[2];
    const void* as1 = d_in[3];
    const void* ad1 = d_in[4];
    const void* b1  = d_in[5];
    const void* W2  = d_in[6];
    const void* as2 = d_in[7];
    const void* ad2 = d_in[8];
    const void* b2  = d_in[9];

    int E  = in_sizes[1] / 2;          // 800000
    int n1 = in_sizes[2];              // 128*64
    int n2 = in_sizes[6];              // 64*64
    int K1 = n1 / F_OUT;               // 128
    int N  = in_sizes[0] / K1;         // 50000
    int total = E + N;
    int NB = (N + BW - 1) / BW;        // 196 buckets
    int nchunks = (total + CH - 1) / CH; // 208 chunks
    int M = NB * nchunks;              // table size
    int nbM = (M + 1023) / 1024;

    size_t nf = (size_t)N * F_OUT;
    char* wsb = (char*)d_ws;
    unsigned short* h   = (unsigned short*)wsb;                 // nf bf16
    unsigned short* x1b = h + nf;                               // nf bf16
    unsigned short* wt1 = x1b + nf;                             // n1 bf16
    unsigned short* wt2 = wt1 + n1;                             // n2 bf16
    float* a_s  = (float*)(wt2 + n2 + ((n1 + n2) & 1));         // N f32 (align)
    float* a_d  = a_s + N;
    float* vecs = a_d + N;                                      // 384 f32
    float* cAs1 = vecs,       *cAd1 = vecs + 64,  *cB1 = vecs + 128;
    float* cAs2 = vecs + 192, *cAd2 = vecs + 256, *cB2 = vecs + 320;
    int* flags    = (int*)(vecs + 384);
    int* row_ptr  = flags + 8;            // N+1
    int* eidx     = row_ptr + N + 1;      // total
    unsigned* staged = (unsigned*)(eidx + total); // total
    int* table    = (int*)(staged + total);       // M
    int* bsum     = table + M;                    // nbM

    int blkGemm = (N + 63) / 64;       // 4 waves x 16 rows per block
    int blkNode = (N + 3) / 4;

    prep_all<<<1, 1024, 0, stream>>>((const unsigned*)W1, (const unsigned*)ei,
                                     W1, as1, ad1, b1, W2, as2, ad2, b2,
                                     wt1, wt2, vecs, n1, n2, K1, flags);

    // ---- CSR build: bucket counting sort (no global atomics) ----
    bucket_count<<<nchunks, 256, 0, stream>>>(ei, table, E, total, NB, nchunks, flags);
    scan_phaseA<<<nbM, 256, 0, stream>>>(table, bsum, M);
    scan_phaseB<<<1, 64, 0, stream>>>(bsum, nbM, row_ptr + N, total);  // row_ptr[N] = E+N
    scan_phaseC<<<nbM, 256, 0, stream>>>(table, bsum, M);
    stage_scatter<<<nchunks, 256, 0, stream>>>(ei, table, staged, E, total, NB, nchunks, flags);
    bucket_csr<<<NB, 256, 0, stream>>>(staged, table, row_ptr, eidx, N, total, NB, nchunks);

    // ---- layer 1 ----
    mfma_gemm<128><<<blkGemm, 256, 0, stream>>>(x, wt1, cAs1, cAd1, h, a_s, a_d, N, flags, 2);
    node_gather<<<blkNode, 256, 0, stream>>>(row_ptr, eidx, a_s, a_d, h, cB1, x1b, N, flags, 0);

    // ---- layer 2 ----
    mfma_gemm<64><<<blkGemm, 256, 0, stream>>>(x1b, wt2, cAs2, cAd2, h, a_s, a_d, N, flags, 1);
    node_gather<<<blkNode, 256, 0, stream>>>(row_ptr, eidx, a_s, a_d, h, cB2, d_out, N, flags, 1);
}

// Round 11
// 229.710 us; speedup vs baseline: 3.9697x; 1.0117x over previous
//
#include <hip/hip_runtime.h>
#include <hip/hip_bf16.h>

#define F_OUT 64
#define NEG_SLOPE 0.2f
#define SOFT_EPS 1e-16f
#define BW 256          // nodes per bucket (i_local fits in 8 bits)
#define CH 8192         // edges per chunk
#define TH 512          // threads for bucket_count / stage_scatter

typedef short short8 __attribute__((ext_vector_type(8)));
typedef float floatx4 __attribute__((ext_vector_type(4)));
typedef unsigned short ushort4v __attribute__((ext_vector_type(4)));

__device__ __forceinline__ unsigned short f2bf_bits(float v) {
    __hip_bfloat16 hb = __float2bfloat16(v);
    return *(unsigned short*)&hb;
}
__device__ __forceinline__ float bf_bits2f(unsigned short u) {
    __hip_bfloat16 hb = *(__hip_bfloat16*)&u;
    return __bfloat162float(hb);
}

__device__ __forceinline__ float read_any(const void* src, int off, int bf) {
    return bf ? __bfloat162float(((const __hip_bfloat16*)src)[off])
              : ((const float*)src)[off];
}

// ---------- fused dtype detection + weight prep (single block) ----------
// flags[0] = 1 if float tensors are bf16, 0 if float32
// flags[1] = 1 if edge_index is int64, 0 if int32
__global__ void prep_all(const unsigned* __restrict__ wbits, const unsigned* __restrict__ ebits,
                         const void* w1, const void* as1, const void* ad1, const void* b1,
                         const void* w2, const void* as2, const void* ad2, const void* b2,
                         unsigned short* __restrict__ wt1, unsigned short* __restrict__ wt2,
                         float* __restrict__ vecs, int n1, int n2, int K1,
                         int* __restrict__ flags) {
    __shared__ int cnt_bf, cnt_zero, sh_bf;
    int tid = threadIdx.x;
    if (tid == 0) { cnt_bf = 0; cnt_zero = 0; }
    __syncthreads();
    int lb = 0, lz = 0;
    for (int k = tid; k < 4096; k += 1024) {
        unsigned w = wbits[k];
        unsigned e = (w >> 7) & 0xFFu;
        if (e >= 0x60u && e <= 0x7Eu) lb++;
        if (ebits[2 * k + 1] == 0u) lz++;
    }
    atomicAdd(&cnt_bf, lb);
    atomicAdd(&cnt_zero, lz);
    __syncthreads();
    if (tid == 0) {
        int bf = (cnt_bf > 2048) ? 1 : 0;
        flags[0] = bf;
        flags[1] = (cnt_zero > 2048) ? 1 : 0;
        sh_bf = bf;
    }
    __syncthreads();
    int bf = sh_bf;
    int total = n1 + n2 + 384;
    for (int t = tid; t < total; t += 1024) {
        if (t < n1) {                       // wt1[n*K1 + k] = W1[k*64 + n]
            int n = t / K1, k = t - n * K1;
            wt1[t] = f2bf_bits(read_any(w1, k * F_OUT + n, bf));
        } else if (t < n1 + n2) {           // wt2[n*64 + k] = W2[k*64 + n]
            int u = t - n1;
            int n = u >> 6, k = u & 63;
            wt2[u] = f2bf_bits(read_any(w2, k * F_OUT + n, bf));
        } else {
            int u = t - n1 - n2;
            const void* src[6] = {as1, ad1, b1, as2, ad2, b2};
            vecs[u] = read_any(src[u >> 6], u & 63, bf);
        }
    }
}

__device__ __forceinline__ int get_idx(const void* ei, int i64, long long pos) {
    return i64 ? (int)((const long long*)ei)[pos] : ((const int*)ei)[pos];
}

// ---------- locality-aware CSR build (counting sort by 256-node buckets) ----------
// Self-loops appended at t >= E (i = j = t - E).

// Per-chunk bucket histogram -> table[b * nchunks + chunk]  (bucket-major).
__global__ void bucket_count(const void* __restrict__ ei, int* __restrict__ table,
                             int E, int total, int NB, int nchunks,
                             const int* __restrict__ flags) {
    __shared__ int cnt[1024];
    for (int k = threadIdx.x; k < NB; k += TH) cnt[k] = 0;
    __syncthreads();
    int i64 = flags[1];
    int base = blockIdx.x * CH;
    int lim = base + CH < total ? base + CH : total;
    for (int t = base + threadIdx.x; t < lim; t += TH) {
        int i = t < E ? get_idx(ei, i64, (long long)E + t) : t - E;
        atomicAdd(&cnt[i >> 8], 1);
    }
    __syncthreads();
    for (int k = threadIdx.x; k < NB; k += TH) table[k * nchunks + blockIdx.x] = cnt[k];
}

// ---- hierarchical exclusive scan (parallel across blocks; a single-block
// scan was a 65 µs one-CU latency trap in R9 — keep this 3-phase form) ----
__global__ void scan_phaseA(const int* __restrict__ src, int* __restrict__ bsum, int n) {
    int idx = blockIdx.x * 1024 + threadIdx.x * 4;
    int s = 0;
#pragma unroll
    for (int j = 0; j < 4; ++j) { int k = idx + j; if (k < n) s += src[k]; }
#pragma unroll
    for (int off = 1; off < 64; off <<= 1) s += __shfl_xor(s, off);
    __shared__ int ws[4];
    int lane = threadIdx.x & 63, w = threadIdx.x >> 6;
    if (lane == 0) ws[w] = s;
    __syncthreads();
    if (threadIdx.x == 0) bsum[blockIdx.x] = ws[0] + ws[1] + ws[2] + ws[3];
}

// One wave; also writes *extra = extra_val (row_ptr[N] = E+N).
__global__ void scan_phaseB(int* __restrict__ bsum, int nb,
                            int* __restrict__ extra, int extra_val) {
    int lane = threadIdx.x;  // 64 threads
    int carry = 0;
    for (int base = 0; base < nb; base += 64) {
        int idx = base + lane;
        int orig = (idx < nb) ? bsum[idx] : 0;
        int v = orig;
#pragma unroll
        for (int off = 1; off < 64; off <<= 1) {
            int t = __shfl_up(v, off);
            if (lane >= off) v += t;
        }
        int chunk_total = __shfl(v, 63);
        if (idx < nb) bsum[idx] = v - orig + carry;
        carry += chunk_total;
    }
    if (lane == 0 && extra) *extra = extra_val;
}

// In-place safe: each block reads its own 1024 region before writing it.
__global__ void scan_phaseC(int* __restrict__ data, const int* __restrict__ bsum, int n) {
    int idx = blockIdx.x * 1024 + threadIdx.x * 4;
    int lane = threadIdx.x & 63, w = threadIdx.x >> 6;
    int d[4];
#pragma unroll
    for (int j = 0; j < 4; ++j) d[j] = (idx + j < n) ? data[idx + j] : 0;
    int tot = d[0] + d[1] + d[2] + d[3];
    int v = tot;
#pragma unroll
    for (int off = 1; off < 64; off <<= 1) {
        int t = __shfl_up(v, off);
        if (lane >= off) v += t;
    }
    __shared__ int wtot[4];
    if (lane == 63) wtot[w] = v;
    __syncthreads();
    int woff = 0;
    for (int k = 0; k < w; ++k) woff += wtot[k];
    int excl = v - tot + woff + bsum[blockIdx.x];
    int o[4];
    o[0] = excl; o[1] = o[0] + d[0]; o[2] = o[1] + d[1]; o[3] = o[2] + d[2];
#pragma unroll
    for (int j = 0; j < 4; ++j)
        if (idx + j < n) data[idx + j] = o[j];
}

// Per-chunk scatter into bucket-major staging: staged[pos] = (i_local<<24) | j.
__global__ void stage_scatter(const void* __restrict__ ei, const int* __restrict__ table,
                              unsigned* __restrict__ staged, int E, int total,
                              int NB, int nchunks, const int* __restrict__ flags) {
    __shared__ int cur[1024];
    for (int k = threadIdx.x; k < NB; k += TH) cur[k] = table[k * nchunks + blockIdx.x];
    __syncthreads();
    int i64 = flags[1];
    int base = blockIdx.x * CH;
    int lim = base + CH < total ? base + CH : total;
    for (int t = base + threadIdx.x; t < lim; t += TH) {
        int i = t < E ? get_idx(ei, i64, (long long)E + t) : t - E;
        int j = t < E ? get_idx(ei, i64, t) : t - E;
        int pos = atomicAdd(&cur[i >> 8], 1);
        staged[pos] = ((unsigned)(i & 255) << 24) | (unsigned)j;
    }
}

// One block per bucket: LDS degree hist -> LDS scan -> row_ptr and in-segment eidx.
__global__ void bucket_csr(const unsigned* __restrict__ staged, const int* __restrict__ table,
                           int* __restrict__ row_ptr, int* __restrict__ eidx,
                           int N, int total, int NB, int nchunks) {
    __shared__ int ldeg[BW];
    __shared__ int lcur[BW];
    __shared__ int wtot[4];
    int b = blockIdx.x;
    int t = threadIdx.x;
    int seg_beg = table[b * nchunks];
    int seg_end = (b + 1 < NB) ? table[(b + 1) * nchunks] : total;
    ldeg[t] = 0;
    __syncthreads();
    for (int p = seg_beg + t; p < seg_end; p += 256)
        atomicAdd(&ldeg[staged[p] >> 24], 1);
    __syncthreads();
    int lane = t & 63, w = t >> 6;
    int d = ldeg[t];
    int v = d;
#pragma unroll
    for (int off = 1; off < 64; off <<= 1) {
        int u = __shfl_up(v, off);
        if (lane >= off) v += u;
    }
    if (lane == 63) wtot[w] = v;
    __syncthreads();
    int woff = 0;
    for (int k = 0; k < w; ++k) woff += wtot[k];
    int excl = v - d + woff;
    int node = b * BW + t;
    if (node < N) row_ptr[node] = seg_beg + excl;
    lcur[t] = excl;
    __syncthreads();
    for (int p = seg_beg + t; p < seg_end; p += 256) {
        unsigned pk = staged[p];
        int pos = atomicAdd(&lcur[pk >> 24], 1);
        eidx[seg_beg + pos] = (int)(pk & 0xFFFFFFu);
    }
}

// ---------- MFMA GEMM: h = x @ W (h stored bf16), fused attention dots ----------
template <int K>
__global__ void mfma_gemm(const void* __restrict__ xv, const unsigned short* __restrict__ Wt,
                          const float* __restrict__ att_s, const float* __restrict__ att_d,
                          unsigned short* __restrict__ h, float* __restrict__ a_s,
                          float* __restrict__ a_d, int N,
                          const int* __restrict__ flags, int in_mode) {
    int lane = threadIdx.x & 63;
    int m0 = (blockIdx.x * 4 + (threadIdx.x >> 6)) * 16;
    if (m0 >= N) return;
    int c = lane & 15, quad = lane >> 4;
    int arow = m0 + c;
    if (arow >= N) arow = N - 1;
    int bf = (in_mode == 2) ? flags[0] : in_mode;

    floatx4 acc0 = {0.f, 0.f, 0.f, 0.f};
    floatx4 acc1 = acc0, acc2 = acc0, acc3 = acc0;

    for (int kc = 0; kc < K; kc += 32) {
        int ka = kc + quad * 8;
        short8 a;
        if (bf) {
            a = *(const short8*)((const unsigned short*)xv + (size_t)arow * K + ka);
        } else {
            const float* xp = (const float*)xv + (size_t)arow * K + ka;
#pragma unroll
            for (int j = 0; j < 8; ++j) a[j] = (short)f2bf_bits(xp[j]);
        }
        short8 b0 = *(const short8*)(Wt + (size_t)(c)      * K + ka);
        short8 b1 = *(const short8*)(Wt + (size_t)(16 + c) * K + ka);
        short8 b2 = *(const short8*)(Wt + (size_t)(32 + c) * K + ka);
        short8 b3 = *(const short8*)(Wt + (size_t)(48 + c) * K + ka);
        acc0 = __builtin_amdgcn_mfma_f32_16x16x32_bf16(a, b0, acc0, 0, 0, 0);
        acc1 = __builtin_amdgcn_mfma_f32_16x16x32_bf16(a, b1, acc1, 0, 0, 0);
        acc2 = __builtin_amdgcn_mfma_f32_16x16x32_bf16(a, b2, acc2, 0, 0, 0);
        acc3 = __builtin_amdgcn_mfma_f32_16x16x32_bf16(a, b3, acc3, 0, 0, 0);
    }

    float as0 = att_s[c],      as1 = att_s[16 + c], as2 = att_s[32 + c], as3 = att_s[48 + c];
    float ad0 = att_d[c],      ad1 = att_d[16 + c], ad2 = att_d[32 + c], ad3 = att_d[48 + c];
#pragma unroll
    for (int reg = 0; reg < 4; ++reg) {
        int row = m0 + quad * 4 + reg;
        float vs = acc0[reg] * as0 + acc1[reg] * as1 + acc2[reg] * as2 + acc3[reg] * as3;
        float vd = acc0[reg] * ad0 + acc1[reg] * ad1 + acc2[reg] * ad2 + acc3[reg] * ad3;
#pragma unroll
        for (int off = 1; off < 16; off <<= 1) {
            vs += __shfl_xor(vs, off);
            vd += __shfl_xor(vd, off);
        }
        if (row < N) {
            if (c == 0) { a_s[row] = vs; a_d[row] = vd; }
            unsigned short* hr = h + (size_t)row * F_OUT + c;
            hr[0]  = f2bf_bits(acc0[reg]);
            hr[16] = f2bf_bits(acc1[reg]);
            hr[32] = f2bf_bits(acc2[reg]);
            hr[48] = f2bf_bits(acc3[reg]);
        }
    }
}

// ---------- fused softmax + gather + bias; 1 wave per node ----------
// Quad-parallel rows: each lane loads ushort4 (8 B), 16 lanes cover one h-row,
// so one global_load_dwordx2 fetches 4 edges' rows. Per 4 edges: 2 shuffles +
// 1 load + 16 FMA. Final combine: xor-16/32 shuffle-add, quad-0 lanes store.
// mode 0: x1_bf16 = bf16(relu(acc/sum + bias))
// mode 1: out = acc/sum + bias, stored bf16 or f32 per flags[0]
__global__ void node_gather(const int* __restrict__ row_ptr, const int* __restrict__ eidx,
                            const float* __restrict__ a_s, const float* __restrict__ a_d,
                            const unsigned short* __restrict__ h, const float* __restrict__ bias,
                            void* __restrict__ out, int N,
                            const int* __restrict__ flags, int mode) {
    int lane = threadIdx.x & 63;
    int i = blockIdx.x * 4 + (threadIdx.x >> 6);
    if (i >= N) return;
    int quad = lane >> 4, c = lane & 15;
    int beg = row_ptr[i];
    int end = row_ptr[i + 1];
    float ad = a_d[i];
    float se = 0.f;
    floatx4 acc[4];
#pragma unroll
    for (int k = 0; k < 4; ++k) acc[k] = (floatx4){0.f, 0.f, 0.f, 0.f};

    for (int p = beg; p < end; p += 64) {
        int tile = end - p; if (tile > 64) tile = 64;
        int jm = eidx[p + (lane < tile ? lane : tile - 1)];
        float wm = 0.f;
        if (lane < tile) {
            float e = a_s[jm] + ad;
            wm = __expf(e > 0.f ? e : NEG_SLOPE * e);
        }
        se += wm;
        for (int e = 0; e < tile; e += 16) {
#pragma unroll
            for (int k = 0; k < 4; ++k) {
                if (e + 4 * k < tile) {                 // wave-uniform branch
                    int idx = e + 4 * k + quad;
                    int srcl = idx < tile ? idx : tile - 1;
                    int jk = __shfl(jm, srcl);
                    float wk = __shfl(wm, srcl);
                    if (idx >= tile) wk = 0.f;
                    ushort4v hv = *(const ushort4v*)(h + (size_t)jk * F_OUT + (c << 2));
                    acc[k][0] += wk * bf_bits2f(hv[0]);
                    acc[k][1] += wk * bf_bits2f(hv[1]);
                    acc[k][2] += wk * bf_bits2f(hv[2]);
                    acc[k][3] += wk * bf_bits2f(hv[3]);
                }
            }
        }
    }
#pragma unroll
    for (int off = 1; off < 64; off <<= 1) se += __shfl_xor(se, off);
    floatx4 A = (acc[0] + acc[1]) + (acc[2] + acc[3]);
#pragma unroll
    for (int m = 0; m < 4; ++m) {
        A[m] += __shfl_xor(A[m], 16);
        A[m] += __shfl_xor(A[m], 32);
    }
    if (quad == 0) {                     // lanes 0..15 write cols 4c..4c+3
        int col = c << 2;
        float inv = 1.f / (se + SOFT_EPS);
        float v0 = A[0] * inv + bias[col];
        float v1 = A[1] * inv + bias[col + 1];
        float v2 = A[2] * inv + bias[col + 2];
        float v3 = A[3] * inv + bias[col + 3];
        size_t o = (size_t)i * F_OUT + col;
        if (mode == 0) {
            ushort4v ov;
            ov[0] = f2bf_bits(v0 > 0.f ? v0 : 0.f);
            ov[1] = f2bf_bits(v1 > 0.f ? v1 : 0.f);
            ov[2] = f2bf_bits(v2 > 0.f ? v2 : 0.f);
            ov[3] = f2bf_bits(v3 > 0.f ? v3 : 0.f);
            *(ushort4v*)((unsigned short*)out + o) = ov;
        } else if (flags[0]) {
            ushort4v ov;
            ov[0] = f2bf_bits(v0); ov[1] = f2bf_bits(v1);
            ov[2] = f2bf_bits(v2); ov[3] = f2bf_bits(v3);
            *(ushort4v*)((unsigned short*)out + o) = ov;
        } else {
            floatx4 ov = {v0, v1, v2, v3};
            *(floatx4*)((float*)out + o) = ov;
        }
    }
}

extern "C" void kernel_launch(void* const* d_in, const int* in_sizes, int n_in,
                              void* d_out, int out_size, void* d_ws, size_t ws_size,
                              hipStream_t stream) {
    const void* x   = d_in[0];
    const void* ei  = d_in[1];
    const void* W1  = d_in[2];
    const void* as1 = d_in[3];
    const void* ad1 = d_in[4];
    const void* b1  = d_in[5];
    const void* W2  = d_in[6];
    const void* as2 = d_in[7];
    const void* ad2 = d_in[8];
    const void* b2  = d_in[9];

    int E  = in_sizes[1] / 2;          // 800000
    int n1 = in_sizes[2];              // 128*64
    int n2 = in_sizes[6];              // 64*64
    int K1 = n1 / F_OUT;               // 128
    int N  = in_sizes[0] / K1;         // 50000
    int total = E + N;
    int NB = (N + BW - 1) / BW;        // 196 buckets
    int nchunks = (total + CH - 1) / CH; // 104 chunks
    int M = NB * nchunks;              // table size
    int nbM = (M + 1023) / 1024;

    size_t nf = (size_t)N * F_OUT;
    char* wsb = (char*)d_ws;
    unsigned short* h   = (unsigned short*)wsb;                 // nf bf16
    unsigned short* x1b = h + nf;                               // nf bf16
    unsigned short* wt1 = x1b + nf;                             // n1 bf16
    unsigned short* wt2 = wt1 + n1;                             // n2 bf16
    float* a_s  = (float*)(wt2 + n2 + ((n1 + n2) & 1));         // N f32 (align)
    float* a_d  = a_s + N;
    float* vecs = a_d + N;                                      // 384 f32
    float* cAs1 = vecs,       *cAd1 = vecs + 64,  *cB1 = vecs + 128;
    float* cAs2 = vecs + 192, *cAd2 = vecs + 256, *cB2 = vecs + 320;
    int* flags    = (int*)(vecs + 384);
    int* row_ptr  = flags + 8;            // N+1
    int* eidx     = row_ptr + N + 1;      // total
    unsigned* staged = (unsigned*)(eidx + total); // total
    int* table    = (int*)(staged + total);       // M
    int* bsum     = table + M;                    // nbM

    int blkGemm = (N + 63) / 64;       // 4 waves x 16 rows per block
    int blkNode = (N + 3) / 4;

    prep_all<<<1, 1024, 0, stream>>>((const unsigned*)W1, (const unsigned*)ei,
                                     W1, as1, ad1, b1, W2, as2, ad2, b2,
                                     wt1, wt2, vecs, n1, n2, K1, flags);

    // ---- CSR build: bucket counting sort (no global atomics) ----
    bucket_count<<<nchunks, TH, 0, stream>>>(ei, table, E, total, NB, nchunks, flags);
    scan_phaseA<<<nbM, 256, 0, stream>>>(table, bsum, M);
    scan_phaseB<<<1, 64, 0, stream>>>(bsum, nbM, row_ptr + N, total);  // row_ptr[N] = E+N
    scan_phaseC<<<nbM, 256, 0, stream>>>(table, bsum, M);
    stage_scatter<<<nchunks, TH, 0, stream>>>(ei, table, staged, E, total, NB, nchunks, flags);
    bucket_csr<<<NB, 256, 0, stream>>>(staged, table, row_ptr, eidx, N, total, NB, nchunks);

    // ---- layer 1 ----
    mfma_gemm<128><<<blkGemm, 256, 0, stream>>>(x, wt1, cAs1, cAd1, h, a_s, a_d, N, flags, 2);
    node_gather<<<blkNode, 256, 0, stream>>>(row_ptr, eidx, a_s, a_d, h, cB1, x1b, N, flags, 0);

    // ---- layer 2 ----
    mfma_gemm<64><<<blkGemm, 256, 0, stream>>>(x1b, wt2, cAs2, cAd2, h, a_s, a_d, N, flags, 1);
    node_gather<<<blkNode, 256, 0, stream>>>(row_ptr, eidx, a_s, a_d, h, cB2, d_out, N, flags, 1);
}